// Round 6
// baseline (237.028 us; speedup 1.0000x reference)
//
#include <hip/hip_runtime.h>
#include <cstdint>
#include <cstddef>

#define S_LEN   2048
#define D_MODEL 1536
#define NH      24
#define HDIM    64
#define WINDOW  512
#define NANCH   4

typedef __attribute__((ext_vector_type(8))) short short8;
typedef __attribute__((ext_vector_type(4))) float floatx4;

#define ASYNC_COPY16(g, l) \
    __builtin_amdgcn_global_load_lds((const __attribute__((address_space(1))) uint32_t*)(g), \
                                     (__attribute__((address_space(3))) uint32_t*)(l), 16, 0, 0)

static __device__ __forceinline__ ushort f32_to_bf16(float f) {
    uint32_t u = __float_as_uint(f);
    uint32_t r = (u + 0x7FFFu + ((u >> 16) & 1u)) >> 16;
    return (ushort)r;
}

// ---------------- prep: RoPE cos/sin table + spike mask normalize ----------------
__global__ __launch_bounds__(256) void prep_kernel(
    const uint8_t* __restrict__ raw, int* __restrict__ norm, float* __restrict__ cs) {
    if (blockIdx.x < 256) {
        int idx = blockIdx.x * 256 + threadIdx.x;   // 65536 = s*32 + i
        int s = idx >> 5, i = idx & 31;
        float inv_freq = expf(-(float)i * 0.2878231366242557f); // ln(10000)/32
        float c, sn;
        sincosf((float)s * inv_freq, &sn, &c);
        cs[s * 64 + i]      = c;
        cs[s * 64 + 32 + i] = sn;
        return;
    }
    __shared__ int sh[2];
    if (threadIdx.x == 0) { sh[0] = 0; sh[1] = 0; }
    __syncthreads();
    int f = 0, nz = 0;
    for (int i = threadIdx.x; i < S_LEN; i += 256) {
        uint8_t b = raw[i];
        if ((i & 3) == 3 && b == 0x3f) f++;          // 1.0f high byte
        if ((i & 3) != 0 && b != 0)    nz++;
    }
    if (f)  atomicAdd(&sh[0], f);
    if (nz) atomicAdd(&sh[1], nz);
    __syncthreads();
    const int mode = (sh[0] > 0) ? 2 : ((sh[1] > 0) ? 1 : 0);  // 2=f32 1=u8 0=i32
    for (int i = threadIdx.x; i < S_LEN; i += 256) {
        int v;
        if (mode == 2)      v = (((const float*)raw)[i] != 0.0f) ? 1 : 0;
        else if (mode == 1) v = raw[i] ? 1 : 0;
        else                v = (((const int*)raw)[i] != 0) ? 1 : 0;
        norm[i] = v;
    }
}

// ---------------- fp32 -> bf16 convert: x + Wq + Wk + Wv in one launch ----------------
__global__ void f2bf4_kernel(const float* __restrict__ x,
                             const float* __restrict__ wq, const float* __restrict__ wk,
                             const float* __restrict__ wv,
                             ushort* __restrict__ xb, ushort* __restrict__ wb,
                             int xq4, int wq4) {
    const int which = blockIdx.y;
    const size_t w_elems = (size_t)D_MODEL * D_MODEL;
    const float* src; ushort* dst; int n4;
    if (which == 0)      { src = x;  dst = xb;               n4 = xq4; }
    else if (which == 1) { src = wq; dst = wb;               n4 = wq4; }
    else if (which == 2) { src = wk; dst = wb + w_elems;     n4 = wq4; }
    else                 { src = wv; dst = wb + 2 * w_elems; n4 = wq4; }
    int i = blockIdx.x * blockDim.x + threadIdx.x;
    if (i >= n4) return;
    float4 v = ((const float4*)src)[i];
    ushort4 o;
    o.x = f32_to_bf16(v.x);
    o.y = f32_to_bf16(v.y);
    o.z = f32_to_bf16(v.z);
    o.w = f32_to_bf16(v.w);
    ((ushort4*)dst)[i] = o;
}

// ---------------- QKV projection + fused RoPE ----------------
// z=0 -> Qb bf16 [H][S][64] (roped, pre-scaled by 0.125); z=1 -> Kb bf16 (roped);
// z=2 -> Vt bf16 [H][64][S]
__global__ __launch_bounds__(256) void gemm_qkv_kernel(
    const ushort* __restrict__ xb,   // [2048][1536] bf16
    const ushort* __restrict__ wb,   // [3][1536][1536] bf16
    const float*  __restrict__ cs,   // [2048][64] cos|sin table
    ushort* __restrict__ Qb, ushort* __restrict__ Kb, ushort* __restrict__ Vt)
{
    const int tm = blockIdx.x;   // 0..15  (S/128)
    const int tn = blockIdx.y;   // 0..11  (E/128)
    const int z  = blockIdx.z;   // 0..2
    const ushort* W = wb + (size_t)z * (D_MODEL * (size_t)D_MODEL);

    __shared__ __align__(16) ushort As[128 * 32];  // 8 KB, row-major, 64B rows
    __shared__ __align__(16) ushort Bs[128 * 32];

    const int tid  = threadIdx.x;
    const int wave = tid >> 6;
    const int lane = tid & 63;

    const int srow = wave * 32 + (lane >> 2);
    const int scol = (lane & 3) * 8;               // ushorts
    const ushort* gA0 = xb + (size_t)(tm * 128 + srow) * D_MODEL + scol;
    const ushort* gA1 = gA0 + (size_t)16 * D_MODEL;
    const ushort* gB0 = W  + (size_t)(tn * 128 + srow) * D_MODEL + scol;
    const ushort* gB1 = gB0 + (size_t)16 * D_MODEL;
    ushort* lA0 = &As[wave * 1024];
    ushort* lA1 = &As[wave * 1024 + 512];
    ushort* lB0 = &Bs[wave * 1024];
    ushort* lB1 = &Bs[wave * 1024 + 512];

    const int wm = (wave >> 1) * 64;
    const int wn = (wave & 1) * 64;
    const int lrow  = lane & 15;
    const int quadk = (lane >> 4) * 8;

    floatx4 acc[4][4];
#pragma unroll
    for (int i = 0; i < 4; ++i)
#pragma unroll
        for (int j = 0; j < 4; ++j)
            acc[i][j] = (floatx4){0.f, 0.f, 0.f, 0.f};

    for (int kt = 0; kt < D_MODEL / 32; ++kt) {
        __syncthreads();
        ASYNC_COPY16(gA0 + kt * 32, lA0);
        ASYNC_COPY16(gA1 + kt * 32, lA1);
        ASYNC_COPY16(gB0 + kt * 32, lB0);
        ASYNC_COPY16(gB1 + kt * 32, lB1);
        __syncthreads();

        short8 af[4], bf[4];
#pragma unroll
        for (int i = 0; i < 4; ++i) af[i] = *(const short8*)(&As[(wm + i * 16 + lrow) * 32 + quadk]);
#pragma unroll
        for (int j = 0; j < 4; ++j) bf[j] = *(const short8*)(&Bs[(wn + j * 16 + lrow) * 32 + quadk]);
#pragma unroll
        for (int i = 0; i < 4; ++i)
#pragma unroll
            for (int j = 0; j < 4; ++j)
                acc[i][j] = __builtin_amdgcn_mfma_f32_16x16x32_bf16(af[i], bf[j], acc[i][j], 0, 0, 0);
    }

    const int r0 = (lane >> 4) * 4;
    const int c0 = lane & 15;
    if (z < 2) {
        // fused RoPE; Q additionally pre-scaled by softmax 1/8 (exact, exponent-only)
        ushort* O = (z == 0) ? Qb : Kb;
        const float qscale = (z == 0) ? 0.125f : 1.0f;
#pragma unroll
        for (int i = 0; i < 4; ++i) {
#pragma unroll
            for (int j = 0; j < 2; ++j) {
                const int col = tn * 128 + wn + j * 16 + c0;
                const int h = col >> 6, d0 = col & 63;     // d0 in [0,32)
#pragma unroll
                for (int r = 0; r < 4; ++r) {
                    const int row = tm * 128 + wm + i * 16 + r0 + r;  // s
                    const float c  = cs[row * 64 + d0];
                    const float sn = cs[row * 64 + 32 + d0];
                    const float x0 = acc[i][j][r];
                    const float x1 = acc[i][j + 2][r];
                    const size_t base = ((size_t)h * S_LEN + row) * HDIM;
                    O[base + d0]      = f32_to_bf16((x0 * c - x1 * sn) * qscale);
                    O[base + d0 + 32] = f32_to_bf16((x1 * c + x0 * sn) * qscale);
                }
            }
        }
    } else {
        // V transposed bf16: Vt[h][d][s]
#pragma unroll
        for (int i = 0; i < 4; ++i) {
#pragma unroll
            for (int j = 0; j < 4; ++j) {
                int col = tn * 128 + wn + j * 16 + c0;
                int h = col >> 6, d = col & 63;
                int row0 = tm * 128 + wm + i * 16 + r0;
                ushort4 o;
                o.x = f32_to_bf16(acc[i][j][0]);
                o.y = f32_to_bf16(acc[i][j][1]);
                o.z = f32_to_bf16(acc[i][j][2]);
                o.w = f32_to_bf16(acc[i][j][3]);
                *(ushort4*)&Vt[((size_t)h * HDIM + d) * S_LEN + row0] = o;
            }
        }
    }
}

// ---------------- flash attention: MFMA, barrier-free, pipelined ----------------
// Per-wave independent (Pst is per-wave). XCD-swizzled block mapping: each XCD
// owns 3 whole heads so its K/V working set (~3 MB) fits the 4 MB per-XCD L2.
__global__ __launch_bounds__(256) void flash_attn_kernel(
    const ushort* __restrict__ Qb,   // [H][S][64] bf16 roped, pre-scaled 1/8
    const ushort* __restrict__ Kb,   // [H][S][64] bf16 roped
    const ushort* __restrict__ Vt,   // [H][64][S] bf16
    const int*   __restrict__ spike, // [S] 0/1
    float* __restrict__ out)         // [S][1536]
{
    // XCD-aware remap (heuristic: linear block id round-robins XCDs)
    const int lb  = blockIdx.x + (blockIdx.y << 5);  // 0..767
    const int h   = (lb & 7) * 3 + ((lb >> 3) >> 5); // 3 heads per XCD
    const int qt  = (lb >> 3) & 31;
    const int qs  = qt * 64;
    const int tid  = threadIdx.x;
    const int wave = tid >> 6;
    const int lane = tid & 63;
    const int quad = lane >> 4;
    const int l16  = lane & 15;

    __shared__ __align__(16) ushort Pst[4][16 * 72];   // per-wave P staging

    const ushort* Qp = Qb + ((size_t)h * S_LEN + qs + wave * 16 + l16) * HDIM;
    const short8 qf0 = *(const short8*)(Qp + quad * 8);
    const short8 qf1 = *(const short8*)(Qp + 32 + quad * 8);

    const int qrow0 = qs + wave * 16 + quad * 4;

    float m_i[4], l_i[4];
    floatx4 Oacc[4];
#pragma unroll
    for (int r = 0; r < 4; ++r) { m_i[r] = -INFINITY; l_i[r] = 0.f; }
#pragma unroll
    for (int j = 0; j < 4; ++j) Oacc[j] = (floatx4){0.f, 0.f, 0.f, 0.f};

    const int lo = (qs > WINDOW ? qs - WINDOW : 0) >> 6;
    const int has_anchor = (lo > 0) ? 1 : 0;
    const int nt = has_anchor ? (qt - lo + 2) : (qt - lo + 1);

    const size_t krow = (size_t)h * S_LEN;
    const size_t vrow = (size_t)h * HDIM;

    // preload tile 0 (anchor tile 0 if present, else tile lo==0)
    int tcur = 0;
    short8 kf[4][2];
    int spk[4];
#pragma unroll
    for (int j = 0; j < 4; ++j) {
        const ushort* Kp = Kb + (krow + j * 16 + l16) * HDIM;
        kf[j][0] = *(const short8*)(Kp + quad * 8);
        kf[j][1] = *(const short8*)(Kp + 32 + quad * 8);
        spk[j] = spike[j * 16 + l16];
    }

    ushort* myP = Pst[wave];

    for (int i = 0; i < nt; ++i) {
        const int kbase = tcur * 64;

        // ---- issue V loads for current tile (consumed at PV, end of iter) ----
        short8 vf[4][2];
#pragma unroll
        for (int j = 0; j < 4; ++j) {
            const ushort* Vp = Vt + (vrow + j * 16 + l16) * S_LEN + kbase + quad * 8;
            vf[j][0] = *(const short8*)Vp;
            vf[j][1] = *(const short8*)(Vp + 32);
        }

        // ---- QK^T (K frags already in registers) ----
        floatx4 Sacc[4];
#pragma unroll
        for (int j = 0; j < 4; ++j) {
            floatx4 s = (floatx4){0.f, 0.f, 0.f, 0.f};
            s = __builtin_amdgcn_mfma_f32_16x16x32_bf16(qf0, kf[j][0], s, 0, 0, 0);
            s = __builtin_amdgcn_mfma_f32_16x16x32_bf16(qf1, kf[j][1], s, 0, 0, 0);
            Sacc[j] = s;
        }

        // ---- issue K prefetch for next tile (in flight across softmax) ----
        int tnext = (i + 1 < nt) ? (has_anchor ? (lo + i) : (i + 1)) : tcur;
        short8 kn[4][2];
        int spn[4];
        {
            const int nb = tnext * 64;
#pragma unroll
            for (int j = 0; j < 4; ++j) {
                const ushort* Kp = Kb + (krow + nb + j * 16 + l16) * HDIM;
                kn[j][0] = *(const short8*)(Kp + quad * 8);
                kn[j][1] = *(const short8*)(Kp + 32 + quad * 8);
                spn[j] = spike[nb + j * 16 + l16];
            }
        }

        // ---- mask + online softmax (Q pre-scaled: Sacc is already scores) ----
        float p[4][4];   // [j][r]
#pragma unroll
        for (int r = 0; r < 4; ++r) {
            const int q = qrow0 + r;
            float mx = -INFINITY;
#pragma unroll
            for (int j = 0; j < 4; ++j) {
                const int k = kbase + j * 16 + l16;
                const bool valid = (k <= q) && (((q - k) <= WINDOW) || (k < NANCH)) && (spk[j] != 0);
                float s = valid ? Sacc[j][r] : -INFINITY;
                p[j][r] = s;
                mx = fmaxf(mx, s);
            }
            mx = fmaxf(mx, __shfl_xor(mx, 1));
            mx = fmaxf(mx, __shfl_xor(mx, 2));
            mx = fmaxf(mx, __shfl_xor(mx, 4));
            mx = fmaxf(mx, __shfl_xor(mx, 8));
            const float mnew = fmaxf(m_i[r], mx);
            const float alpha = (m_i[r] == -INFINITY) ? 0.f : __expf(m_i[r] - mnew);
            float rs = 0.f;
#pragma unroll
            for (int j = 0; j < 4; ++j) {
                float w = (p[j][r] == -INFINITY) ? 0.f : __expf(p[j][r] - mnew);
                p[j][r] = w;
                rs += w;
            }
            rs += __shfl_xor(rs, 1);
            rs += __shfl_xor(rs, 2);
            rs += __shfl_xor(rs, 4);
            rs += __shfl_xor(rs, 8);
            l_i[r] = l_i[r] * alpha + rs;
            m_i[r] = mnew;
#pragma unroll
            for (int j = 0; j < 4; ++j) Oacc[j][r] *= alpha;
        }

        // ---- P -> per-wave LDS (C-layout -> A-layout); no barriers needed ----
#pragma unroll
        for (int r = 0; r < 4; ++r)
#pragma unroll
            for (int j = 0; j < 4; ++j)
                myP[(quad * 4 + r) * 72 + j * 16 + l16] = f32_to_bf16(p[j][r]);

        // ---- P @ V ----
#pragma unroll
        for (int kk = 0; kk < 2; ++kk) {
            const short8 pf = *(const short8*)(myP + l16 * 72 + kk * 32 + quad * 8);
#pragma unroll
            for (int j = 0; j < 4; ++j)
                Oacc[j] = __builtin_amdgcn_mfma_f32_16x16x32_bf16(pf, vf[j][kk], Oacc[j], 0, 0, 0);
        }

        // rotate prefetched K
#pragma unroll
        for (int j = 0; j < 4; ++j) {
            kf[j][0] = kn[j][0];
            kf[j][1] = kn[j][1];
            spk[j] = spn[j];
        }
        tcur = tnext;
    }

    // ---- epilogue: normalize, apply spike[q], write ----
#pragma unroll
    for (int r = 0; r < 4; ++r) {
        const int q = qrow0 + r;
        const float inv = (l_i[r] > 0.f && spike[q] != 0) ? (1.0f / l_i[r]) : 0.f;
#pragma unroll
        for (int j = 0; j < 4; ++j)
            out[(size_t)q * D_MODEL + h * HDIM + j * 16 + l16] = Oacc[j][r] * inv;
    }
}

extern "C" void kernel_launch(void* const* d_in, const int* in_sizes, int n_in,
                              void* d_out, int out_size, void* d_ws, size_t ws_size,
                              hipStream_t stream) {
    const float* x     = (const float*)d_in[0];
    const uint8_t* spike_raw = (const uint8_t*)d_in[1];
    const float* Wq    = (const float*)d_in[2];
    const float* Wk    = (const float*)d_in[3];
    const float* Wv    = (const float*)d_in[4];
    float* out = (float*)d_out;

    const size_t xb_elems = (size_t)S_LEN * D_MODEL;          // 3,145,728
    const size_t w_elems  = (size_t)D_MODEL * D_MODEL;        // 2,359,296
    const size_t hs_elems = (size_t)NH * S_LEN * HDIM;        // 3,145,728

    char* ws = (char*)d_ws;
    size_t off = 0;
    ushort* xb = (ushort*)(ws + off); off += xb_elems * 2;        // 6.29 MB
    ushort* wb = (ushort*)(ws + off); off += 3 * w_elems * 2;     // 14.16 MB
    ushort* Qb = (ushort*)(ws + off); off += hs_elems * 2;        // 6.29 MB
    ushort* Kb = (ushort*)(ws + off); off += hs_elems * 2;        // 6.29 MB
    ushort* Vt = (ushort*)(ws + off); off += hs_elems * 2;        // 6.29 MB
    float*  cst = (float*)(ws + off); off += (size_t)S_LEN * 64 * 4;  // 512 KB
    int* spike_i = (int*)(ws + off); off += S_LEN * 4;
    if (ws_size < off) return;

    // 0) RoPE table + spike normalize
    prep_kernel<<<257, 256, 0, stream>>>(spike_raw, spike_i, cst);

    // 1) fp32 -> bf16 (x, Wq, Wk, Wv)
    {
        int xq4 = (int)(xb_elems / 4);
        int wq4 = (int)(w_elems / 4);
        f2bf4_kernel<<<dim3((xq4 + 255) / 256, 4), 256, 0, stream>>>(
            x, Wq, Wk, Wv, xb, wb, xq4, wq4);
    }

    // 2) QKV projections (bf16 MFMA, global_load_lds staging) + fused RoPE
    gemm_qkv_kernel<<<dim3(S_LEN / 128, D_MODEL / 128, 3), 256, 0, stream>>>(
        xb, wb, cst, Qb, Kb, Vt);

    // 3) flash attention (MFMA, barrier-free, pipelined, XCD-swizzled)
    flash_attn_kernel<<<dim3(S_LEN / 64, NH), 256, 0, stream>>>(Qb, Kb, Vt, spike_i, out);
}